// Round 5
// baseline (5557.848 us; speedup 1.0000x reference)
//
#include <hip/hip_runtime.h>
#include <hip/hip_bf16.h>
#include <stdint.h>

#define NDIM 256
#define NB_MAX 2048   // max dst-tiles (N <= 131072)

typedef __bf16 bf16_t;
typedef __bf16 bf16x8 __attribute__((ext_vector_type(8)));
typedef float f32x4 __attribute__((ext_vector_type(4)));

__device__ __forceinline__ float bf2f(uint32_t u16) {
    union { uint32_t i; float f; } v; v.i = u16 << 16; return v.f;
}
__device__ __forceinline__ uint32_t f2bf(float f) {
    union { float f; uint32_t i; } v; v.f = f;
    uint32_t r = v.i + 0x7fff + ((v.i >> 16) & 1);
    return r >> 16;
}

// ---------------- dst-tile bucketing ----------------

__global__ __launch_bounds__(1024) void k_hist(const int* __restrict__ dst,
                                               int* __restrict__ gbins, int E, int NB) {
    __shared__ int h[NB_MAX];
    for (int i = threadIdx.x; i < NB; i += 1024) h[i] = 0;
    __syncthreads();
    for (int i = blockIdx.x * 1024 + threadIdx.x; i < E; i += gridDim.x * 1024)
        atomicAdd(&h[dst[i] >> 6], 1);
    __syncthreads();
    for (int i = threadIdx.x; i < NB; i += 1024) {
        int v = h[i];
        if (v) atomicAdd(&gbins[i], v);
    }
}

// single-wave exclusive scan over NB bins -> base (NB+1) and cursor copy
__global__ void k_scan1(const int* __restrict__ gbins, int* __restrict__ base,
                        int* __restrict__ cursor, int NB) {
    int lane = threadIdx.x;   // 64 threads
    int per = (NB + 63) / 64;
    int b0 = lane * per;
    int s = 0;
    for (int i = 0; i < per; ++i) { int idx = b0 + i; if (idx < NB) s += gbins[idx]; }
    int inc = s;
    for (int off = 1; off < 64; off <<= 1) {
        int u = __shfl_up(inc, off);
        if (lane >= off) inc += u;
    }
    int run = inc - s;   // exclusive
    for (int i = 0; i < per; ++i) {
        int idx = b0 + i;
        if (idx < NB) {
            int v = gbins[idx];
            base[idx] = run; cursor[idx] = run;
            run += v;
        }
    }
    if (lane == 63) base[NB] = run;
}

// pack: src (17b) | local_dst (6b) << 17
__global__ void k_scatter(const int* __restrict__ src, const int* __restrict__ dst,
                          int* __restrict__ cursor, uint32_t* __restrict__ ebuf, int E) {
    int i = blockIdx.x * blockDim.x + threadIdx.x;
    if (i < E) {
        int d = dst[i];
        int slot = atomicAdd(&cursor[d >> 6], 1);
        ebuf[slot] = (uint32_t)src[i] | ((uint32_t)(d & 63) << 17);
    }
}

// ---------------- conversions ----------------

__global__ void k_cvt(const float4* __restrict__ in, ushort4* __restrict__ out, int n4) {
    int i = blockIdx.x * blockDim.x + threadIdx.x;
    if (i < n4) {
        float4 v = in[i];
        ushort4 o;
        o.x = (uint16_t)f2bf(v.x); o.y = (uint16_t)f2bf(v.y);
        o.z = (uint16_t)f2bf(v.z); o.w = (uint16_t)f2bf(v.w);
        out[i] = o;
    }
}

__global__ void k_cvtcopy(const float4* __restrict__ in, float4* __restrict__ outf,
                          ushort4* __restrict__ outb, int n4) {
    int i = blockIdx.x * blockDim.x + threadIdx.x;
    if (i < n4) {
        float4 v = in[i];
        outf[i] = v;
        ushort4 o;
        o.x = (uint16_t)f2bf(v.x); o.y = (uint16_t)f2bf(v.y);
        o.z = (uint16_t)f2bf(v.z); o.w = (uint16_t)f2bf(v.w);
        outb[i] = o;
    }
}

__global__ void k_wt4(const float* __restrict__ W0, const float* __restrict__ W1,
                      const float* __restrict__ W2, const float* __restrict__ W3,
                      uint16_t* __restrict__ Wt) {
    int which = blockIdx.y;
    const float* W = (which == 0) ? W0 : (which == 1) ? W1 : (which == 2) ? W2 : W3;
    uint16_t* O = Wt + (size_t)which * NDIM * NDIM;
    int n = blockIdx.x, k = threadIdx.x;
    O[n * NDIM + k] = (uint16_t)f2bf(W[k * NDIM + n]);
}

// ---------------- aggregation: LDS f32 accumulators per 64-node dst-tile ----------------
// Swizzled LDS layout: channel ch of node ld lives at acc[ld*256 + (ch&3)*64 + (ch>>2)];
// lane L's 4 ds_add_f32 then hit bank L%32 (2-way alias across the wave = free).

__global__ __launch_bounds__(512) void k_aggr(
        const uint16_t* __restrict__ x, const uint32_t* __restrict__ ebuf,
        const int* __restrict__ base, uint16_t* __restrict__ neigh, int N) {
    __shared__ float acc[64 * NDIM];
    __shared__ int degc[64];
    int tid = threadIdx.x;
    for (int i = tid; i < 64 * NDIM / 4; i += 512)
        ((float4*)acc)[i] = make_float4(0.f, 0.f, 0.f, 0.f);
    if (tid < 64) degc[tid] = 0;
    __syncthreads();

    int b0 = base[blockIdx.x], b1 = base[blockIdx.x + 1];
    int w = tid >> 6, lane = tid & 63;

    for (int c = b0 + w * 64; c < b1; c += 512) {
        int rem = b1 - c; if (rem > 64) rem = 64;
        uint32_t il = (lane < rem) ? ebuf[c + lane] : 0u;
#pragma unroll 4
        for (int j = 0; j < rem; ++j) {
            uint32_t u = __shfl(il, j);
            int s  = (int)(u & 0x1FFFF);
            int ld = (int)(u >> 17);
            uint2 v = *(const uint2*)(x + (size_t)s * NDIM + lane * 4);
            float* a = acc + ld * NDIM;
            atomicAdd(a +       lane, bf2f(v.x & 0xffff));
            atomicAdd(a +  64 + lane, bf2f(v.x >> 16));
            atomicAdd(a + 128 + lane, bf2f(v.y & 0xffff));
            atomicAdd(a + 192 + lane, bf2f(v.y >> 16));
            if (lane == 0) atomicAdd(&degc[ld], 1);
        }
    }
    __syncthreads();

    int nodebase = blockIdx.x * 64;
    for (int uidx = tid; uidx < 64 * 32; uidx += 512) {
        int node = uidx >> 5, seg = uidx & 31;
        int g = nodebase + node;
        if (g < N) {
            int dg = degc[node];
            float inv = (dg > 0) ? (1.f / (float)dg) : 0.f;
            const float* a = acc + node * NDIM;
            float vals[8];
#pragma unroll
            for (int t = 0; t < 8; ++t) {
                int ch = seg * 8 + t;
                vals[t] = a[((ch & 3) << 6) | (ch >> 2)] * inv;
            }
            uint4 o;
            o.x = f2bf(vals[0]) | (f2bf(vals[1]) << 16);
            o.y = f2bf(vals[2]) | (f2bf(vals[3]) << 16);
            o.z = f2bf(vals[4]) | (f2bf(vals[5]) << 16);
            o.w = f2bf(vals[6]) | (f2bf(vals[7]) << 16);
            *(uint4*)(neigh + (size_t)g * NDIM + seg * 8) = o;
        }
    }
}

// ---------------- fused dual-source bf16 MFMA GEMM ----------------

template <int RELU, int WB>
__global__ __launch_bounds__(256) void k_gemm(
        const uint16_t* __restrict__ A1, const uint16_t* __restrict__ B1t,
        const uint16_t* __restrict__ A2, const uint16_t* __restrict__ B2t,
        const float* __restrict__ bias, float* __restrict__ C,
        uint16_t* __restrict__ Cb, int M) {
    constexpr int LST = 40;
    __shared__ __align__(16) bf16_t As[128 * LST];
    __shared__ __align__(16) bf16_t Bs[128 * LST];
    int tid  = threadIdx.x;
    int w    = tid >> 6, lane = tid & 63;
    int wm   = w >> 1,   wn   = w & 1;
    int row0 = blockIdx.x * 128;
    int col0 = blockIdx.y * 128;

    f32x4 acc[4][4];
#pragma unroll
    for (int m = 0; m < 4; ++m)
#pragma unroll
        for (int n = 0; n < 4; ++n)
            acc[m][n] = (f32x4){0.f, 0.f, 0.f, 0.f};

    int r0s = tid >> 2, s0s = tid & 3;
    int r1s = r0s + 64, s1s = s0s;
    int kseg = lane >> 4;
    int rr   = lane & 15;

    for (int pair = 0; pair < 2; ++pair) {
        const uint16_t* A  = pair ? A2 : A1;
        const uint16_t* Bt = pair ? B2t : B1t;
        for (int k0 = 0; k0 < NDIM; k0 += 32) {
            int gra0 = min(row0 + r0s, M - 1);
            int gra1 = min(row0 + r1s, M - 1);
            uint4 va0 = *(const uint4*)(A  + (size_t)gra0 * NDIM + k0 + s0s * 8);
            uint4 va1 = *(const uint4*)(A  + (size_t)gra1 * NDIM + k0 + s1s * 8);
            uint4 vb0 = *(const uint4*)(Bt + (size_t)(col0 + r0s) * NDIM + k0 + s0s * 8);
            uint4 vb1 = *(const uint4*)(Bt + (size_t)(col0 + r1s) * NDIM + k0 + s1s * 8);
            __syncthreads();
            *(uint4*)(As + r0s * LST + s0s * 8) = va0;
            *(uint4*)(As + r1s * LST + s1s * 8) = va1;
            *(uint4*)(Bs + r0s * LST + s0s * 8) = vb0;
            *(uint4*)(Bs + r1s * LST + s1s * 8) = vb1;
            __syncthreads();

            bf16x8 af[4], bfr[4];
#pragma unroll
            for (int m = 0; m < 4; ++m)
                af[m] = *(const bf16x8*)(As + (wm * 64 + m * 16 + rr) * LST + kseg * 8);
#pragma unroll
            for (int n = 0; n < 4; ++n)
                bfr[n] = *(const bf16x8*)(Bs + (wn * 64 + n * 16 + rr) * LST + kseg * 8);
#pragma unroll
            for (int m = 0; m < 4; ++m)
#pragma unroll
                for (int n = 0; n < 4; ++n)
                    acc[m][n] = __builtin_amdgcn_mfma_f32_16x16x32_bf16(
                        af[m], bfr[n], acc[m][n], 0, 0, 0);
        }
    }

    int rbase = (lane >> 4) * 4;
    int cc    = lane & 15;
#pragma unroll
    for (int n = 0; n < 4; ++n) {
        int col = col0 + wn * 64 + n * 16 + cc;
        float bb = bias[col];
#pragma unroll
        for (int m = 0; m < 4; ++m) {
#pragma unroll
            for (int r = 0; r < 4; ++r) {
                int row = row0 + wm * 64 + m * 16 + rbase + r;
                if (row < M) {
                    float o = acc[m][n][r] + bb;
                    if (RELU) o = fmaxf(o, 0.f);
                    C[(size_t)row * NDIM + col] = o;
                    if (WB) Cb[(size_t)row * NDIM + col] = (uint16_t)f2bf(o);
                }
            }
        }
    }
}

__global__ void k_copy(const float4* __restrict__ in, float4* __restrict__ out, int n4) {
    int i = blockIdx.x * blockDim.x + threadIdx.x;
    if (i < n4) out[i] = in[i];
}

// ---------------- launch ----------------

extern "C" void kernel_launch(void* const* d_in, const int* in_sizes, int n_in,
                              void* d_out, int out_size, void* d_ws, size_t ws_size,
                              hipStream_t stream) {
    const float* feat = (const float*)d_in[0];
    const int*   src  = (const int*)d_in[1];
    const int*   dst  = (const int*)d_in[2];
    const float* Ws0  = (const float*)d_in[3];
    const float* Wn0  = (const float*)d_in[4];
    const float* b0   = (const float*)d_in[5];
    const float* Ws1  = (const float*)d_in[6];
    const float* Wn1  = (const float*)d_in[7];
    const float* b1   = (const float*)d_in[8];

    const int N = in_sizes[0] / NDIM;   // 100000
    const int E = in_sizes[1];          // 1600000
    const int NB = (N + 63) / 64;       // 1563 dst-tiles

    float* out    = (float*)d_out;
    float* out_x  = out;
    float* out_a1 = out + (size_t)N * NDIM;
    float* out_h2 = out + 2 * (size_t)N * NDIM;

    // ws: gbins | base | cursor | ebuf | Wt x4 | bf16 bufs x4
    int*      gbins  = (int*)d_ws;
    int*      basep  = gbins + NB_MAX;
    int*      cursor = basep + NB_MAX + 1;
    uint32_t* ebuf   = (uint32_t*)(cursor + NB_MAX);
    uint16_t* Wt     = (uint16_t*)(ebuf + E);
    uint16_t* Ws0t = Wt;
    uint16_t* Wn0t = Wt + 1 * (size_t)NDIM * NDIM;
    uint16_t* Ws1t = Wt + 2 * (size_t)NDIM * NDIM;
    uint16_t* Wn1t = Wt + 3 * (size_t)NDIM * NDIM;
    uint16_t* wsbuf = Wt + 4 * (size_t)NDIM * NDIM;

    size_t NK = (size_t)N * NDIM;
    size_t need = ((char*)(wsbuf + 4 * NK)) - (char*)d_ws;
    bool ws_ok = ws_size >= need;

    uint16_t *featb, *neigh1b, *a1b, *neigh2b;
    if (ws_ok) {
        featb   = wsbuf;
        neigh1b = wsbuf + NK;
        a1b     = wsbuf + 2 * NK;
        neigh2b = wsbuf + 3 * NK;
    } else {
        featb   = (uint16_t*)out_h2;
        neigh1b = (uint16_t*)out_h2 + NK;
        a1b     = (uint16_t*)out_x;
        neigh2b = (uint16_t*)out_x + NK;
    }

    // bucket build
    hipMemsetAsync(gbins, 0, (size_t)NB * sizeof(int), stream);
    k_hist<<<64, 1024, 0, stream>>>(dst, gbins, E, NB);
    k_scan1<<<1, 64, 0, stream>>>(gbins, basep, cursor, NB);
    k_scatter<<<(E + 255) / 256, 256, 0, stream>>>(src, dst, cursor, ebuf, E);

    dim3 gw(NDIM, 4);
    k_wt4<<<gw, NDIM, 0, stream>>>(Ws0, Wn0, Ws1, Wn1, Wt);

    int n4 = N * NDIM / 4;
    if (ws_ok) {
        k_cvtcopy<<<(n4 + 255) / 256, 256, 0, stream>>>(
            (const float4*)feat, (float4*)out_x, (ushort4*)featb, n4);
    } else {
        k_cvt<<<(n4 + 255) / 256, 256, 0, stream>>>((const float4*)feat, (ushort4*)featb, n4);
    }

    dim3 gg((N + 127) / 128, NDIM / 128);

    // layer 1
    k_aggr<<<NB, 512, 0, stream>>>(featb, ebuf, basep, neigh1b, N);
    k_gemm<1, 1><<<gg, 256, 0, stream>>>(featb, Ws0t, neigh1b, Wn0t, b0, out_a1, a1b, N);

    // layer 2
    k_aggr<<<NB, 512, 0, stream>>>(a1b, ebuf, basep, neigh2b, N);
    k_gemm<0, 0><<<gg, 256, 0, stream>>>(a1b, Ws1t, neigh2b, Wn1t, b1, out_h2, nullptr, N);

    if (!ws_ok) {
        k_copy<<<(n4 + 255) / 256, 256, 0, stream>>>((const float4*)feat, (float4*)out_x, n4);
    }
}

// Round 6
// 981.932 us; speedup vs baseline: 5.6601x; 5.6601x over previous
//
#include <hip/hip_runtime.h>
#include <hip/hip_bf16.h>
#include <stdint.h>

#define NDIM 256

typedef __bf16 bf16_t;
typedef __bf16 bf16x8 __attribute__((ext_vector_type(8)));
typedef float f32x4 __attribute__((ext_vector_type(4)));

__device__ __forceinline__ float bf2f(uint32_t u16) {
    union { uint32_t i; float f; } v; v.i = u16 << 16; return v.f;
}
__device__ __forceinline__ uint32_t f2bf(float f) {
    union { float f; uint32_t i; } v; v.f = f;
    uint32_t r = v.i + 0x7fff + ((v.i >> 16) & 1);
    return r >> 16;
}

// ---------------- CSR build (per-node, round-3 known-good) ----------------

__global__ void k_deg(const int* __restrict__ dst, int* __restrict__ deg, int E) {
    int i = blockIdx.x * blockDim.x + threadIdx.x;
    if (i < E) atomicAdd(&deg[dst[i]], 1);
}

__global__ void k_partial(const int* __restrict__ deg, int* __restrict__ partial, int N) {
    __shared__ int sm[256];
    int i = blockIdx.x * 256 + threadIdx.x;
    sm[threadIdx.x] = (i < N) ? deg[i] : 0;
    __syncthreads();
    for (int s = 128; s > 0; s >>= 1) {
        if (threadIdx.x < s) sm[threadIdx.x] += sm[threadIdx.x + s];
        __syncthreads();
    }
    if (threadIdx.x == 0) partial[blockIdx.x] = sm[0];
}

__global__ void k_scan_partial(int* partial, int nb) {
    __shared__ int sm[512];
    int t = threadIdx.x;
    int v = (t < nb) ? partial[t] : 0;
    sm[t] = v;
    __syncthreads();
    for (int off = 1; off < 512; off <<= 1) {
        int u = (t >= off) ? sm[t - off] : 0;
        __syncthreads();
        sm[t] += u;
        __syncthreads();
    }
    if (t < nb) partial[t] = sm[t] - v;   // exclusive
}

__global__ void k_scan_block(const int* __restrict__ deg, const int* __restrict__ partial,
                             int* __restrict__ offsets, int* __restrict__ cursor,
                             float* __restrict__ invdeg, int N) {
    __shared__ int sm[256];
    int t = threadIdx.x;
    int i = blockIdx.x * 256 + t;
    int v = (i < N) ? deg[i] : 0;
    sm[t] = v;
    __syncthreads();
    for (int off = 1; off < 256; off <<= 1) {
        int u = (t >= off) ? sm[t - off] : 0;
        __syncthreads();
        sm[t] += u;
        __syncthreads();
    }
    if (i < N) {
        int excl = sm[t] - v + partial[blockIdx.x];
        offsets[i] = excl;
        cursor[i]  = excl;
        invdeg[i]  = (v > 0) ? (1.0f / (float)v) : 0.0f;
    }
}

__global__ void k_place(const int* __restrict__ src, const int* __restrict__ dst,
                        int* __restrict__ cursor, int* __restrict__ srcsorted, int E) {
    int i = blockIdx.x * blockDim.x + threadIdx.x;
    if (i < E) {
        int p = atomicAdd(&cursor[dst[i]], 1);
        srcsorted[p] = src[i];
    }
}

// ---------------- conversions ----------------

__global__ void k_cvt(const float4* __restrict__ in, ushort4* __restrict__ out, int n4) {
    int i = blockIdx.x * blockDim.x + threadIdx.x;
    if (i < n4) {
        float4 v = in[i];
        ushort4 o;
        o.x = (uint16_t)f2bf(v.x); o.y = (uint16_t)f2bf(v.y);
        o.z = (uint16_t)f2bf(v.z); o.w = (uint16_t)f2bf(v.w);
        out[i] = o;
    }
}

__global__ void k_cvtcopy(const float4* __restrict__ in, float4* __restrict__ outf,
                          ushort4* __restrict__ outb, int n4) {
    int i = blockIdx.x * blockDim.x + threadIdx.x;
    if (i < n4) {
        float4 v = in[i];
        outf[i] = v;
        ushort4 o;
        o.x = (uint16_t)f2bf(v.x); o.y = (uint16_t)f2bf(v.y);
        o.z = (uint16_t)f2bf(v.z); o.w = (uint16_t)f2bf(v.w);
        outb[i] = o;
    }
}

__global__ void k_wt4(const float* __restrict__ W0, const float* __restrict__ W1,
                      const float* __restrict__ W2, const float* __restrict__ W3,
                      uint16_t* __restrict__ Wt) {
    int which = blockIdx.y;
    const float* W = (which == 0) ? W0 : (which == 1) ? W1 : (which == 2) ? W2 : W3;
    uint16_t* O = Wt + (size_t)which * NDIM * NDIM;
    int n = blockIdx.x, k = threadIdx.x;
    O[n * NDIM + k] = (uint16_t)f2bf(W[k * NDIM + n]);
}

// ---------------- aggregation: wave per node, broadcast index load ----------------
// Whole wave handles one edge per step: index load is same-address (1 request,
// broadcast), row gather is 64 lanes x 8B = 512B coalesced. Lane owns channels
// [lane*4, lane*4+4) in f32 registers. unroll 8 -> 8 index->row chains in flight.
// No LDS, no atomics, no cross-lane ops.

__global__ __launch_bounds__(256) void k_aggr(
        const uint16_t* __restrict__ x, const int* __restrict__ srcsorted,
        const int* __restrict__ offsets, const int* __restrict__ deg,
        const float* __restrict__ invdeg, uint16_t* __restrict__ neigh, int N) {
    int node = blockIdx.x * 4 + (threadIdx.x >> 6);
    if (node >= N) return;
    int lane = threadIdx.x & 63;
    int beg = offsets[node];
    int d   = deg[node];
    const uint16_t* __restrict__ xoff = x + lane * 4;

    float a0 = 0.f, a1 = 0.f, a2 = 0.f, a3 = 0.f;
#pragma unroll 8
    for (int j = 0; j < d; ++j) {
        int s = srcsorted[beg + j];                       // wave-uniform -> broadcast
        uint2 v = *(const uint2*)(xoff + (size_t)s * NDIM);
        a0 += bf2f(v.x & 0xffff);
        a1 += bf2f(v.x >> 16);
        a2 += bf2f(v.y & 0xffff);
        a3 += bf2f(v.y >> 16);
    }

    float sc = invdeg[node];
    uint2 o;
    o.x = f2bf(a0 * sc) | (f2bf(a1 * sc) << 16);
    o.y = f2bf(a2 * sc) | (f2bf(a3 * sc) << 16);
    *(uint2*)(neigh + (size_t)node * NDIM + lane * 4) = o;
}

// ---------------- fused dual-source bf16 MFMA GEMM (round-2/3 known-good) ----------------

template <int RELU, int WB>
__global__ __launch_bounds__(256) void k_gemm(
        const uint16_t* __restrict__ A1, const uint16_t* __restrict__ B1t,
        const uint16_t* __restrict__ A2, const uint16_t* __restrict__ B2t,
        const float* __restrict__ bias, float* __restrict__ C,
        uint16_t* __restrict__ Cb, int M) {
    constexpr int LST = 40;
    __shared__ __align__(16) bf16_t As[128 * LST];
    __shared__ __align__(16) bf16_t Bs[128 * LST];
    int tid  = threadIdx.x;
    int w    = tid >> 6, lane = tid & 63;
    int wm   = w >> 1,   wn   = w & 1;
    int row0 = blockIdx.x * 128;
    int col0 = blockIdx.y * 128;

    f32x4 acc[4][4];
#pragma unroll
    for (int m = 0; m < 4; ++m)
#pragma unroll
        for (int n = 0; n < 4; ++n)
            acc[m][n] = (f32x4){0.f, 0.f, 0.f, 0.f};

    int r0s = tid >> 2, s0s = tid & 3;
    int r1s = r0s + 64, s1s = s0s;
    int kseg = lane >> 4;
    int rr   = lane & 15;

    for (int pair = 0; pair < 2; ++pair) {
        const uint16_t* A  = pair ? A2 : A1;
        const uint16_t* Bt = pair ? B2t : B1t;
        for (int k0 = 0; k0 < NDIM; k0 += 32) {
            int gra0 = min(row0 + r0s, M - 1);
            int gra1 = min(row0 + r1s, M - 1);
            uint4 va0 = *(const uint4*)(A  + (size_t)gra0 * NDIM + k0 + s0s * 8);
            uint4 va1 = *(const uint4*)(A  + (size_t)gra1 * NDIM + k0 + s1s * 8);
            uint4 vb0 = *(const uint4*)(Bt + (size_t)(col0 + r0s) * NDIM + k0 + s0s * 8);
            uint4 vb1 = *(const uint4*)(Bt + (size_t)(col0 + r1s) * NDIM + k0 + s1s * 8);
            __syncthreads();
            *(uint4*)(As + r0s * LST + s0s * 8) = va0;
            *(uint4*)(As + r1s * LST + s1s * 8) = va1;
            *(uint4*)(Bs + r0s * LST + s0s * 8) = vb0;
            *(uint4*)(Bs + r1s * LST + s1s * 8) = vb1;
            __syncthreads();

            bf16x8 af[4], bfr[4];
#pragma unroll
            for (int m = 0; m < 4; ++m)
                af[m] = *(const bf16x8*)(As + (wm * 64 + m * 16 + rr) * LST + kseg * 8);
#pragma unroll
            for (int n = 0; n < 4; ++n)
                bfr[n] = *(const bf16x8*)(Bs + (wn * 64 + n * 16 + rr) * LST + kseg * 8);
#pragma unroll
            for (int m = 0; m < 4; ++m)
#pragma unroll
                for (int n = 0; n < 4; ++n)
                    acc[m][n] = __builtin_amdgcn_mfma_f32_16x16x32_bf16(
                        af[m], bfr[n], acc[m][n], 0, 0, 0);
        }
    }

    int rbase = (lane >> 4) * 4;
    int cc    = lane & 15;
#pragma unroll
    for (int n = 0; n < 4; ++n) {
        int col = col0 + wn * 64 + n * 16 + cc;
        float bb = bias[col];
#pragma unroll
        for (int m = 0; m < 4; ++m) {
#pragma unroll
            for (int r = 0; r < 4; ++r) {
                int row = row0 + wm * 64 + m * 16 + rbase + r;
                if (row < M) {
                    float o = acc[m][n][r] + bb;
                    if (RELU) o = fmaxf(o, 0.f);
                    C[(size_t)row * NDIM + col] = o;
                    if (WB) Cb[(size_t)row * NDIM + col] = (uint16_t)f2bf(o);
                }
            }
        }
    }
}

__global__ void k_copy(const float4* __restrict__ in, float4* __restrict__ out, int n4) {
    int i = blockIdx.x * blockDim.x + threadIdx.x;
    if (i < n4) out[i] = in[i];
}

// ---------------- launch ----------------

extern "C" void kernel_launch(void* const* d_in, const int* in_sizes, int n_in,
                              void* d_out, int out_size, void* d_ws, size_t ws_size,
                              hipStream_t stream) {
    const float* feat = (const float*)d_in[0];
    const int*   src  = (const int*)d_in[1];
    const int*   dst  = (const int*)d_in[2];
    const float* Ws0  = (const float*)d_in[3];
    const float* Wn0  = (const float*)d_in[4];
    const float* b0   = (const float*)d_in[5];
    const float* Ws1  = (const float*)d_in[6];
    const float* Wn1  = (const float*)d_in[7];
    const float* b1   = (const float*)d_in[8];

    const int N = in_sizes[0] / NDIM;   // 100000
    const int E = in_sizes[1];          // 1600000

    float* out    = (float*)d_out;
    float* out_x  = out;
    float* out_a1 = out + (size_t)N * NDIM;
    float* out_h2 = out + 2 * (size_t)N * NDIM;

    // ws: deg | offsets | cursor | invdeg | partial | srcsorted | Wt x4 | bf16 bufs x4
    int*      deg       = (int*)d_ws;
    int*      offsets   = deg + N;
    int*      cursor    = offsets + N;
    float*    invdeg    = (float*)(cursor + N);
    int*      partial   = (int*)(invdeg + N);
    int*      srcsorted = partial + 512;
    uint16_t* Wt        = (uint16_t*)(srcsorted + E);
    uint16_t* Ws0t = Wt;
    uint16_t* Wn0t = Wt + 1 * (size_t)NDIM * NDIM;
    uint16_t* Ws1t = Wt + 2 * (size_t)NDIM * NDIM;
    uint16_t* Wn1t = Wt + 3 * (size_t)NDIM * NDIM;
    uint16_t* wsbuf = Wt + 4 * (size_t)NDIM * NDIM;

    size_t NK = (size_t)N * NDIM;
    size_t need = ((char*)(wsbuf + 4 * NK)) - (char*)d_ws;
    bool ws_ok = ws_size >= need;

    uint16_t *featb, *neigh1b, *a1b, *neigh2b;
    if (ws_ok) {
        featb   = wsbuf;
        neigh1b = wsbuf + NK;
        a1b     = wsbuf + 2 * NK;
        neigh2b = wsbuf + 3 * NK;
    } else {
        featb   = (uint16_t*)out_h2;
        neigh1b = (uint16_t*)out_h2 + NK;
        a1b     = (uint16_t*)out_x;
        neigh2b = (uint16_t*)out_x + NK;
    }

    hipMemsetAsync(deg, 0, (size_t)N * sizeof(int), stream);

    int nb = (N + 255) / 256;
    k_deg<<<(E + 255) / 256, 256, 0, stream>>>(dst, deg, E);
    k_partial<<<nb, 256, 0, stream>>>(deg, partial, N);
    k_scan_partial<<<1, 512, 0, stream>>>(partial, nb);
    k_scan_block<<<nb, 256, 0, stream>>>(deg, partial, offsets, cursor, invdeg, N);
    k_place<<<(E + 255) / 256, 256, 0, stream>>>(src, dst, cursor, srcsorted, E);

    dim3 gw(NDIM, 4);
    k_wt4<<<gw, NDIM, 0, stream>>>(Ws0, Wn0, Ws1, Wn1, Wt);

    int n4 = N * NDIM / 4;
    if (ws_ok) {
        k_cvtcopy<<<(n4 + 255) / 256, 256, 0, stream>>>(
            (const float4*)feat, (float4*)out_x, (ushort4*)featb, n4);
    } else {
        k_cvt<<<(n4 + 255) / 256, 256, 0, stream>>>((const float4*)feat, (ushort4*)featb, n4);
    }

    dim3 gg((N + 127) / 128, NDIM / 128);

    // layer 1
    k_aggr<<<(N + 3) / 4, 256, 0, stream>>>(featb, srcsorted, offsets, deg, invdeg, neigh1b, N);
    k_gemm<1, 1><<<gg, 256, 0, stream>>>(featb, Ws0t, neigh1b, Wn0t, b0, out_a1, a1b, N);

    // layer 2
    k_aggr<<<(N + 3) / 4, 256, 0, stream>>>(a1b, srcsorted, offsets, deg, invdeg, neigh2b, N);
    k_gemm<0, 0><<<gg, 256, 0, stream>>>(a1b, Ws1t, neigh2b, Wn1t, b1, out_h2, nullptr, N);

    if (!ws_ok) {
        k_copy<<<(n4 + 255) / 256, 256, 0, stream>>>((const float4*)feat, (float4*)out_x, n4);
    }
}